// Round 6
// baseline (94.289 us; speedup 1.0000x reference)
//
#include <hip/hip_runtime.h>

#define N_ 256
#define C_ 2048
#define HW_ 49
#define CPB 64
#define NCC (C_/CPB)   // 32
#define POOL_REG 576   // floats per (conv,i2) pool region (swizzled, max fi 571)

// local-channel base in sx: 70 channels (3 halo low, 64 main, 3 halo high).
// Main chunk starts at 148 (16B-aligned for float4); halo-low at 0, gap at 147.
#define CHB(lc) ((lc) * HW_ + ((lc) >= 3 ? 1 : 0))

// Swizzled pool float-index. Logical layout [f][70][8] with 32B rows; the
// half-index (2*lc+half) is XORed with (lc&7): bijective, keeps 16B
// alignment, spreads 8 consecutive rows across all 8 b128 bank-starts.
__device__ __forceinline__ int pool_fi(int f, int lc, int k) {
  return f * POOL_REG + ((((lc << 1) + (k >> 2)) ^ (lc & 7)) << 2) + (k & 3);
}

// ---------------- kernel 1: per-chunk channel-pool partials ----------------
__global__ __launch_bounds__(256) void k_poolc(const float* __restrict__ x,
                                               float* __restrict__ psum,
                                               float* __restrict__ pmax) {
  const int cc = blockIdx.x, n = blockIdx.y;
  const int t = threadIdx.x;
  __shared__ float sx[CPB * HW_];      // 3136
  __shared__ float part_s[HW_][5];
  __shared__ float part_m[HW_][5];

  const float4* xv = (const float4*)(x + ((size_t)n * C_ + (size_t)cc * CPB) * HW_);
  for (int v = t; v < 784; v += 256) {
    float4 q = xv[v];
    sx[v * 4 + 0] = q.x; sx[v * 4 + 1] = q.y;
    sx[v * 4 + 2] = q.z; sx[v * 4 + 3] = q.w;
  }
  __syncthreads();

  if (t < 245) {
    int hw = t / 5, s = t % 5;
    float sm = 0.f, mx = -3.4e38f;
    #pragma unroll
    for (int j = 0; j < 13; ++j) {
      int c = s * 13 + j;
      if (c < CPB) {
        float a = sx[c * HW_ + hw];
        sm += a; mx = fmaxf(mx, a);
      }
    }
    part_s[hw][s] = sm; part_m[hw][s] = mx;
  }
  __syncthreads();

  if (t < HW_) {
    float sm = 0.f, mx = -3.4e38f;
    #pragma unroll
    for (int s = 0; s < 5; ++s) { sm += part_s[t][s]; mx = fmaxf(mx, part_m[t][s]); }
    size_t o = ((size_t)n * NCC + cc) * HW_ + t;
    psum[o] = sm; pmax[o] = mx;
  }
}

// ---------------- kernel 2: reduce chunks, compute g_hw gate per n ----------------
__global__ __launch_bounds__(64) void k_ghw(const float* __restrict__ psum,
                                            const float* __restrict__ pmax,
                                            const float* __restrict__ cw,
                                            const float* __restrict__ cb,
                                            const float* __restrict__ bnw,
                                            const float* __restrict__ bnb,
                                            const float* __restrict__ bnrm,
                                            const float* __restrict__ bnrv,
                                            float* __restrict__ ghw) {
  const int n = blockIdx.x;
  const int t = threadIdx.x;
  __shared__ float p2c[2][13][13];
  __shared__ float s_cw[98];

  for (int i = t; i < 2 * 13 * 13; i += 64) ((float*)p2c)[i] = 0.f;
  for (int i = t; i < 98; i += 64) s_cw[i] = cw[i];
  __syncthreads();

  if (t < HW_) {
    float sm = 0.f, mx = -3.4e38f;
    const float* ps = psum + (size_t)n * NCC * HW_ + t;
    const float* pm = pmax + (size_t)n * NCC * HW_ + t;
    for (int cc = 0; cc < NCC; ++cc) {
      sm += ps[cc * HW_];
      mx = fmaxf(mx, pm[cc * HW_]);
    }
    p2c[0][t / 7 + 3][t % 7 + 3] = sm * (1.f / C_);
    p2c[1][t / 7 + 3][t % 7 + 3] = mx;
  }
  __syncthreads();

  if (t < HW_) {
    int a = t / 7, b = t % 7;
    float y = cb[0];
    #pragma unroll
    for (int i2 = 0; i2 < 2; ++i2)
      #pragma unroll
      for (int p = 0; p < 7; ++p)
        #pragma unroll
        for (int q = 0; q < 7; ++q)
          y += p2c[i2][a + p][b + q] * s_cw[i2 * 49 + p * 7 + q];
    float sc = bnw[0] * rsqrtf(bnrv[0] + 1e-5f);
    y = (y - bnrm[0]) * sc + bnb[0];
    y = fmaxf(y, 0.f);
    ghw[n * HW_ + t] = 1.f / (1.f + __expf(-y));
  }
}

// ---------------- kernel 3: W/H pools, g_ch/g_cw gates, fused multiply ----------------
// LDS: sx[3432] + pool[2304] + gch[448] + gcw[448] + s_ghw[49] = 6681 floats
//    = 26.7 KB -> 6 blocks/CU.
// Wave map: wave w = t>>6: conv = w&1, i2 = w>>1 (both wave-uniform -> weights
// via s_load from global cw), lane = cl in [0,64).
__global__ __launch_bounds__(256, 6) void k_main(const float* __restrict__ x,
    const float* __restrict__ ghw,
    const float* __restrict__ cw, const float* __restrict__ cb,
    const float* __restrict__ bnw, const float* __restrict__ bnb,
    const float* __restrict__ bnrm, const float* __restrict__ bnrv,
    float* __restrict__ out) {
  const int cc = blockIdx.x;
  const int n  = (N_ - 1) - blockIdx.y;
  const int c0 = cc * CPB;
  const int t  = threadIdx.x;

  __shared__ __align__(16) float sx[3432];    // 70ch x 49 (+gap at 147)
  __shared__ __align__(16) float pool[4 * POOL_REG];
  __shared__ float gch[448];                  // [64][7]: conv0 partials, then gates
  __shared__ float gcw[448];                  // conv1
  __shared__ float s_ghw[49];

  const int lane  = t & 63;
  const int convs = __builtin_amdgcn_readfirstlane((t >> 6) & 1);
  const int i2s   = __builtin_amdgcn_readfirstlane(t >> 7);

  // scalar params (s_load path; conv wave-uniform)
  const int bi = 1 + convs;
  const float cb0 = cb[0];
  const float sc_bn = bnw[bi] * rsqrtf(bnrv[bi] + 1e-5f);
  const float rm_bn = bnrm[bi];
  const float sh_bn = bnb[bi];

  // ---- phase 0: stage ----
  if (t < HW_) s_ghw[t] = ghw[n * HW_ + t];
  // halo channels (scalar, long latency — issue early)
  for (int i = t; i < 2 * 3 * HW_; i += 256) {
    int side = i / 147, off = i % 147;
    int lc = side ? (67 + off / HW_) : (off / HW_);
    int c = c0 - 3 + lc;
    float vv = 0.f;
    if (c >= 0 && c < C_) vv = x[((size_t)n * C_ + c) * HW_ + off % HW_];
    sx[CHB(lc) + off % HW_] = vv;
  }
  const float4* xv = (const float4*)(x + ((size_t)n * C_ + c0) * HW_);
  float4* sxv = (float4*)(sx + 148);
  for (int v = t; v < 784; v += 256) sxv[v] = xv[v];
  __syncthreads();

  // ---- phase 1: W-pools / H-pools for all 70 local channels ----
  for (int i = t; i < 70 * 7; i += 256) {
    int lc = i / 7, k = i % 7;
    int base = CHB(lc);
    float s1 = 0.f, m1 = -3.4e38f, s2 = 0.f, m2 = -3.4e38f;
    #pragma unroll
    for (int j = 0; j < 7; ++j) {
      float a = sx[base + k * 7 + j];   // h=k, vary w  -> W-reduction (g_ch input)
      s1 += a; m1 = fmaxf(m1, a);
      float b = sx[base + j * 7 + k];   // w=k, vary h  -> H-reduction (g_cw input)
      s2 += b; m2 = fmaxf(m2, b);
    }
    pool[pool_fi(0, lc, k)] = s1 * (1.f / 7.f);  // conv0 (g_ch): mean over W
    pool[pool_fi(1, lc, k)] = m1;                //               max  over W
    pool[pool_fi(2, lc, k)] = s2 * (1.f / 7.f);  // conv1 (g_cw): mean over H
    pool[pool_fi(3, lc, k)] = m2;                //               max  over H
  }
  __syncthreads();

  // ---- phase 2: conv; wave = (conv, i2), lane = output channel cl ----
  {
    const float* Wb = cw + i2s * 49;                       // wave-uniform -> s_load
    const float* Pb = pool + (convs * 2 + i2s) * POOL_REG;
    float acc[7] = {0.f, 0.f, 0.f, 0.f, 0.f, 0.f, 0.f};
    #pragma unroll
    for (int p = 0; p < 7; ++p) {
      int lr = lane + p;
      int sw = lr & 7;
      float4 r0 = *(const float4*)(Pb + ((((lr << 1)    ) ^ sw) << 2));
      float4 r1 = *(const float4*)(Pb + ((((lr << 1) | 1) ^ sw) << 2));
      float row[7] = {r0.x, r0.y, r0.z, r0.w, r1.x, r1.y, r1.z};
      #pragma unroll
      for (int q = 0; q < 7; ++q) {
        float wvv = Wb[p * 7 + q];
        #pragma unroll
        for (int k = 0; k < 7; ++k) {
          int c = k + q - 3;                 // spatial zero-pad, compile-time
          if (c >= 0 && c < 7) acc[k] += row[c] * wvv;
        }
      }
    }
    float* gbuf = (convs ? gcw : gch) + lane * 7;
    if (i2s == 1) {
      #pragma unroll
      for (int k = 0; k < 7; ++k) gbuf[k] = acc[k];
    }
    __syncthreads();
    if (i2s == 0) {
      #pragma unroll
      for (int k = 0; k < 7; ++k) {
        float y = acc[k] + gbuf[k];
        y = (y + cb0 - rm_bn) * sc_bn + sh_bn;
        y = fmaxf(y, 0.f);
        gbuf[k] = 1.f / (1.f + __expf(-y));
      }
    }
  }
  __syncthreads();

  // ---- phase 3: fused multiply, LDS re-read (b128), float4 stores ----
  float4* outv = (float4*)(out + ((size_t)n * C_ + c0) * HW_);
  for (int v = t; v < 784; v += 256) {
    float4 q = sxv[v];
    int e0 = v * 4;
    int cj = e0 / 49;
    int hw0 = e0 - cj * 49;
    float r0 = q.x, r1 = q.y, r2 = q.z, r3 = q.w;
    {
      int hw = hw0;
      int cjj = cj + (hw >= 49); hw -= (hw >= 49) ? 49 : 0;
      int h = (hw * 37) >> 8, w2 = hw - h * 7;
      r0 *= (s_ghw[hw] + gch[cjj * 7 + h] + gcw[cjj * 7 + w2]) * (1.f / 3.f);
    }
    {
      int hw = hw0 + 1;
      int cjj = cj + (hw >= 49); hw -= (hw >= 49) ? 49 : 0;
      int h = (hw * 37) >> 8, w2 = hw - h * 7;
      r1 *= (s_ghw[hw] + gch[cjj * 7 + h] + gcw[cjj * 7 + w2]) * (1.f / 3.f);
    }
    {
      int hw = hw0 + 2;
      int cjj = cj + (hw >= 49); hw -= (hw >= 49) ? 49 : 0;
      int h = (hw * 37) >> 8, w2 = hw - h * 7;
      r2 *= (s_ghw[hw] + gch[cjj * 7 + h] + gcw[cjj * 7 + w2]) * (1.f / 3.f);
    }
    {
      int hw = hw0 + 3;
      int cjj = cj + (hw >= 49); hw -= (hw >= 49) ? 49 : 0;
      int h = (hw * 37) >> 8, w2 = hw - h * 7;
      r3 *= (s_ghw[hw] + gch[cjj * 7 + h] + gcw[cjj * 7 + w2]) * (1.f / 3.f);
    }
    outv[v] = make_float4(r0, r1, r2, r3);
  }
}

extern "C" void kernel_launch(void* const* d_in, const int* in_sizes, int n_in,
                              void* d_out, int out_size, void* d_ws, size_t ws_size,
                              hipStream_t stream) {
  const float* x    = (const float*)d_in[0];
  const float* cw   = (const float*)d_in[1];
  const float* cb   = (const float*)d_in[2];
  const float* bnw  = (const float*)d_in[3];
  const float* bnb  = (const float*)d_in[4];
  const float* bnrm = (const float*)d_in[5];
  const float* bnrv = (const float*)d_in[6];
  float* out = (float*)d_out;

  float* psum = (float*)d_ws;                       // N*32*49
  float* pmax = psum + (size_t)N_ * NCC * HW_;      // N*32*49
  float* ghw  = pmax + (size_t)N_ * NCC * HW_;      // N*49

  k_poolc<<<dim3(NCC, N_), 256, 0, stream>>>(x, psum, pmax);
  k_ghw<<<dim3(N_), 64, 0, stream>>>(psum, pmax, cw, cb, bnw, bnb, bnrm, bnrv, ghw);
  k_main<<<dim3(NCC, N_), 256, 0, stream>>>(x, ghw, cw, cb, bnw, bnb, bnrm, bnrv, out);
}

// Round 7
// 89.288 us; speedup vs baseline: 1.0560x; 1.0560x over previous
//
#include <hip/hip_runtime.h>

#define N_ 256
#define C_ 2048
#define HW_ 49
#define CPB 64
#define NCC (C_/CPB)   // 32

// local-channel base in sx: 70 channels (3 halo low, 64 main, 3 halo high).
// Main chunk starts at 148 (16B-aligned for float4); halo-low at 0, gap at 147.
#define CHB(lc) ((lc) * HW_ + ((lc) >= 3 ? 1 : 0))

// ---------------- kernel 1: per-chunk channel-pool partials ----------------
__global__ __launch_bounds__(256) void k_poolc(const float* __restrict__ x,
                                               float* __restrict__ psum,
                                               float* __restrict__ pmax) {
  const int cc = blockIdx.x, n = blockIdx.y;
  const int t = threadIdx.x;
  __shared__ float sx[CPB * HW_];      // 3136
  __shared__ float part_s[HW_][5];
  __shared__ float part_m[HW_][5];

  const float4* xv = (const float4*)(x + ((size_t)n * C_ + (size_t)cc * CPB) * HW_);
  for (int v = t; v < 784; v += 256) {
    float4 q = xv[v];
    sx[v * 4 + 0] = q.x; sx[v * 4 + 1] = q.y;
    sx[v * 4 + 2] = q.z; sx[v * 4 + 3] = q.w;
  }
  __syncthreads();

  if (t < 245) {
    int hw = t / 5, s = t % 5;
    float sm = 0.f, mx = -3.4e38f;
    #pragma unroll
    for (int j = 0; j < 13; ++j) {
      int c = s * 13 + j;
      if (c < CPB) {
        float a = sx[c * HW_ + hw];
        sm += a; mx = fmaxf(mx, a);
      }
    }
    part_s[hw][s] = sm; part_m[hw][s] = mx;
  }
  __syncthreads();

  if (t < HW_) {
    float sm = 0.f, mx = -3.4e38f;
    #pragma unroll
    for (int s = 0; s < 5; ++s) { sm += part_s[t][s]; mx = fmaxf(mx, part_m[t][s]); }
    size_t o = ((size_t)n * NCC + cc) * HW_ + t;
    psum[o] = sm; pmax[o] = mx;
  }
}

// ---------------- kernel 2: reduce chunks, compute g_hw gate per n ----------------
__global__ __launch_bounds__(64) void k_ghw(const float* __restrict__ psum,
                                            const float* __restrict__ pmax,
                                            const float* __restrict__ cw,
                                            const float* __restrict__ cb,
                                            const float* __restrict__ bnw,
                                            const float* __restrict__ bnb,
                                            const float* __restrict__ bnrm,
                                            const float* __restrict__ bnrv,
                                            float* __restrict__ ghw) {
  const int n = blockIdx.x;
  const int t = threadIdx.x;
  __shared__ float p2c[2][13][13];
  __shared__ float s_cw[98];

  for (int i = t; i < 2 * 13 * 13; i += 64) ((float*)p2c)[i] = 0.f;
  for (int i = t; i < 98; i += 64) s_cw[i] = cw[i];
  __syncthreads();

  if (t < HW_) {
    float sm = 0.f, mx = -3.4e38f;
    const float* ps = psum + (size_t)n * NCC * HW_ + t;
    const float* pm = pmax + (size_t)n * NCC * HW_ + t;
    for (int cc = 0; cc < NCC; ++cc) {
      sm += ps[cc * HW_];
      mx = fmaxf(mx, pm[cc * HW_]);
    }
    p2c[0][t / 7 + 3][t % 7 + 3] = sm * (1.f / C_);
    p2c[1][t / 7 + 3][t % 7 + 3] = mx;
  }
  __syncthreads();

  if (t < HW_) {
    int a = t / 7, b = t % 7;
    float y = cb[0];
    #pragma unroll
    for (int i2 = 0; i2 < 2; ++i2)
      #pragma unroll
      for (int p = 0; p < 7; ++p)
        #pragma unroll
        for (int q = 0; q < 7; ++q)
          y += p2c[i2][a + p][b + q] * s_cw[i2 * 49 + p * 7 + q];
    float sc = bnw[0] * rsqrtf(bnrv[0] + 1e-5f);
    y = (y - bnrm[0]) * sc + bnb[0];
    y = fmaxf(y, 0.f);
    ghw[n * HW_ + t] = 1.f / (1.f + __expf(-y));
  }
}

// ---------------- kernel 3: W/H pools, g_ch/g_cw gates, fused multiply ----------------
// LDS: sx[3432] + pool_lo[1120] + pool_hi[1120] + gch[448] + gcw[448]
//      + s_w[112] + s_ghw[49] = 6729 floats = 26.9 KB -> 6 blocks/CU.
// Pool rows are 16B (4 floats): b128 bank-start = 4*lc%32 -> 8 distinct starts,
// every bank serves exactly 8 words/wave-instr (the b128 optimum, no conflicts).
__global__ __launch_bounds__(256, 6) void k_main(const float* __restrict__ x,
    const float* __restrict__ ghw,
    const float* __restrict__ cw, const float* __restrict__ cb,
    const float* __restrict__ bnw, const float* __restrict__ bnb,
    const float* __restrict__ bnrm, const float* __restrict__ bnrv,
    float* __restrict__ out) {
  const int cc = blockIdx.x;
  const int n  = (N_ - 1) - blockIdx.y;
  const int c0 = cc * CPB;
  const int t  = threadIdx.x;

  __shared__ __align__(16) float sx[3432];       // 70ch x 49 (+gap at 147)
  __shared__ __align__(16) float pool_lo[1120];  // [4][70][4]: k=0..3, 16B rows
  __shared__ __align__(16) float pool_hi[1120];  // [4][70][4]: k=4..6 (+pad)
  __shared__ float gch[448];                     // [64][7]
  __shared__ float gcw[448];
  __shared__ __align__(16) float s_w[112];       // [2][7][8] weights, q-padded
  __shared__ float s_ghw[49];

  const int conv = t & 1, i2 = (t >> 1) & 1, cl = t >> 2;
  const int bi = 1 + conv;
  const float cb0 = cb[0];
  const float sc_bn = bnw[bi] * rsqrtf(bnrv[bi] + 1e-5f);
  const float rm_bn = bnrm[bi];
  const float sh_bn = bnb[bi];

  // ---- phase 0: stage ----
  if (t < 112) {
    int i2w = t / 56, rem = t % 56, p = rem / 8, q = rem % 8;
    s_w[t] = (q < 7) ? cw[i2w * 49 + p * 7 + q] : 0.f;
  }
  if (t < HW_) s_ghw[t] = ghw[n * HW_ + t];
  // halo channels (scalar, long latency — issue early)
  for (int i = t; i < 2 * 3 * HW_; i += 256) {
    int side = i / 147, off = i % 147;
    int lc = side ? (67 + off / HW_) : (off / HW_);
    int c = c0 - 3 + lc;
    float vv = 0.f;
    if (c >= 0 && c < C_) vv = x[((size_t)n * C_ + c) * HW_ + off % HW_];
    sx[CHB(lc) + off % HW_] = vv;
  }
  const float4* xv = (const float4*)(x + ((size_t)n * C_ + c0) * HW_);
  float4* sxv = (float4*)(sx + 148);
  for (int v = t; v < 784; v += 256) sxv[v] = xv[v];
  __syncthreads();

  // ---- phase 1: W-pools / H-pools for all 70 local channels ----
  for (int i = t; i < 70 * 7; i += 256) {
    int lc = i / 7, k = i % 7;
    int base = CHB(lc);
    float s1 = 0.f, m1 = -3.4e38f, s2 = 0.f, m2 = -3.4e38f;
    #pragma unroll
    for (int j = 0; j < 7; ++j) {
      float a = sx[base + k * 7 + j];   // h=k, vary w  -> W-reduction (g_ch input)
      s1 += a; m1 = fmaxf(m1, a);
      float b = sx[base + j * 7 + k];   // w=k, vary h  -> H-reduction (g_cw input)
      s2 += b; m2 = fmaxf(m2, b);
    }
    float* pb = (k < 4) ? pool_lo : pool_hi;
    int kk = k & 3;
    pb[(0 * 70 + lc) * 4 + kk] = s1 * (1.f / 7.f);  // f=0: conv0 mean
    pb[(1 * 70 + lc) * 4 + kk] = m1;                // f=1: conv0 max
    pb[(2 * 70 + lc) * 4 + kk] = s2 * (1.f / 7.f);  // f=2: conv1 mean
    pb[(3 * 70 + lc) * 4 + kk] = m2;                // f=3: conv1 max
  }
  __syncthreads();

  // ---- phase 2: conv via b128 rows; thread = (conv, i2, cl) ----
  {
    const int f = conv * 2 + i2;
    const float* Wb = s_w + i2 * 56;                 // [7][8]
    float acc[7] = {0.f, 0.f, 0.f, 0.f, 0.f, 0.f, 0.f};
    #pragma unroll
    for (int p = 0; p < 7; ++p) {
      int ri = (f * 70 + cl + p) * 4;
      float4 r0 = *(const float4*)(pool_lo + ri);    // k = 0..3
      float4 r1 = *(const float4*)(pool_hi + ri);    // k = 4..6 (+pad)
      float row[7] = {r0.x, r0.y, r0.z, r0.w, r1.x, r1.y, r1.z};
      float4 w0 = *(const float4*)(Wb + p * 8);      // broadcast b128
      float4 w1 = *(const float4*)(Wb + p * 8 + 4);
      float wr[7] = {w0.x, w0.y, w0.z, w0.w, w1.x, w1.y, w1.z};
      #pragma unroll
      for (int q = 0; q < 7; ++q) {
        #pragma unroll
        for (int k = 0; k < 7; ++k) {
          int c = k + q - 3;                 // compile-time after unroll
          if (c >= 0 && c < 7) acc[k] += row[c] * wr[q];
        }
      }
    }
    float fsum[7];
    #pragma unroll
    for (int k = 0; k < 7; ++k) fsum[k] = acc[k] + __shfl_xor(acc[k], 2, 64);
    if (i2 == 0) {
      float* gp = (conv ? gcw : gch) + cl * 7;
      #pragma unroll
      for (int k = 0; k < 7; ++k) {
        float y = (fsum[k] + cb0 - rm_bn) * sc_bn + sh_bn;
        y = fmaxf(y, 0.f);
        gp[k] = 1.f / (1.f + __expf(-y));
      }
    }
  }
  __syncthreads();

  // ---- phase 3: fused multiply, LDS re-read (b128), float4 stores ----
  float4* outv = (float4*)(out + ((size_t)n * C_ + c0) * HW_);
  for (int v = t; v < 784; v += 256) {
    float4 q = sxv[v];
    int e0 = v * 4;
    int cj = e0 / 49;
    int hw0 = e0 - cj * 49;
    float r0 = q.x, r1 = q.y, r2 = q.z, r3 = q.w;
    {
      int hw = hw0;
      int cjj = cj + (hw >= 49); hw -= (hw >= 49) ? 49 : 0;
      int h = (hw * 37) >> 8, w2 = hw - h * 7;
      r0 *= (s_ghw[hw] + gch[cjj * 7 + h] + gcw[cjj * 7 + w2]) * (1.f / 3.f);
    }
    {
      int hw = hw0 + 1;
      int cjj = cj + (hw >= 49); hw -= (hw >= 49) ? 49 : 0;
      int h = (hw * 37) >> 8, w2 = hw - h * 7;
      r1 *= (s_ghw[hw] + gch[cjj * 7 + h] + gcw[cjj * 7 + w2]) * (1.f / 3.f);
    }
    {
      int hw = hw0 + 2;
      int cjj = cj + (hw >= 49); hw -= (hw >= 49) ? 49 : 0;
      int h = (hw * 37) >> 8, w2 = hw - h * 7;
      r2 *= (s_ghw[hw] + gch[cjj * 7 + h] + gcw[cjj * 7 + w2]) * (1.f / 3.f);
    }
    {
      int hw = hw0 + 3;
      int cjj = cj + (hw >= 49); hw -= (hw >= 49) ? 49 : 0;
      int h = (hw * 37) >> 8, w2 = hw - h * 7;
      r3 *= (s_ghw[hw] + gch[cjj * 7 + h] + gcw[cjj * 7 + w2]) * (1.f / 3.f);
    }
    outv[v] = make_float4(r0, r1, r2, r3);
  }
}

extern "C" void kernel_launch(void* const* d_in, const int* in_sizes, int n_in,
                              void* d_out, int out_size, void* d_ws, size_t ws_size,
                              hipStream_t stream) {
  const float* x    = (const float*)d_in[0];
  const float* cw   = (const float*)d_in[1];
  const float* cb   = (const float*)d_in[2];
  const float* bnw  = (const float*)d_in[3];
  const float* bnb  = (const float*)d_in[4];
  const float* bnrm = (const float*)d_in[5];
  const float* bnrv = (const float*)d_in[6];
  float* out = (float*)d_out;

  float* psum = (float*)d_ws;                       // N*32*49
  float* pmax = psum + (size_t)N_ * NCC * HW_;      // N*32*49
  float* ghw  = pmax + (size_t)N_ * NCC * HW_;      // N*49

  k_poolc<<<dim3(NCC, N_), 256, 0, stream>>>(x, psum, pmax);
  k_ghw<<<dim3(N_), 64, 0, stream>>>(psum, pmax, cw, cb, bnw, bnb, bnrm, bnrv, ghw);
  k_main<<<dim3(NCC, N_), 256, 0, stream>>>(x, ghw, cw, cb, bnw, bnb, bnrm, bnrv, out);
}

// Round 8
// 82.292 us; speedup vs baseline: 1.1458x; 1.0850x over previous
//
#include <hip/hip_runtime.h>

#define N_ 256
#define C_ 2048
#define HW_ 49
#define CPB 64
#define NCC (C_/CPB)    // 32 chunks consumed by k_main
#define NCHUNK 8        // channel-pool partial chunks (256 ch each)

// local-channel base in sx: 70 channels (3 halo low, 64 main, 3 halo high).
// Main chunk starts at 148 (16B-aligned for float4); halo-low at 0, gap at 147.
#define CHB(lc) ((lc) * HW_ + ((lc) >= 3 ? 1 : 0))

// pool float-index: [f][par][35][4] with par = row&1 (even/odd split so that
// P2's B=2 rolling reads keep lane-delta-1 row indices -> 8 balanced b128
// bank-starts). f = conv*2 + i2.
__device__ __forceinline__ int pool_idx(int f, int r, int kk) {
  return (((f << 1) + (r & 1)) * 35 + (r >> 1)) * 4 + kk;
}

// ---------------- kernel 1: channel-pool partials, 256 ch per block ----------------
__global__ __launch_bounds__(256) void k_poolc(const float* __restrict__ x,
                                               float* __restrict__ psum,
                                               float* __restrict__ pmax) {
  const int bc = blockIdx.x, n = blockIdx.y;
  const int t = threadIdx.x;
  __shared__ __align__(16) float sx[CPB * HW_];   // one 64-ch pass
  __shared__ float part_s[HW_][5];
  __shared__ float part_m[HW_][5];

  float sm = 0.f, mx = -3.4e38f;                  // carried across passes
  const int hw = t / 5, s = t % 5;

  const float4* xv = (const float4*)(x + ((size_t)n * C_ + (size_t)bc * 256) * HW_);
  #pragma unroll
  for (int pass = 0; pass < 4; ++pass) {
    float4* sv = (float4*)sx;
    for (int v = t; v < 784; v += 256) sv[v] = xv[pass * 784 + v];
    __syncthreads();
    if (t < 245) {
      #pragma unroll
      for (int j = 0; j < 13; ++j) {
        int c = s * 13 + j;
        if (c < CPB) {
          float a = sx[c * HW_ + hw];
          sm += a; mx = fmaxf(mx, a);
        }
      }
    }
    __syncthreads();
  }
  if (t < 245) { part_s[hw][s] = sm; part_m[hw][s] = mx; }
  __syncthreads();
  if (t < HW_) {
    float s2 = 0.f, m2 = -3.4e38f;
    #pragma unroll
    for (int k = 0; k < 5; ++k) { s2 += part_s[t][k]; m2 = fmaxf(m2, part_m[t][k]); }
    size_t o = ((size_t)n * NCHUNK + bc) * HW_ + t;
    psum[o] = s2; pmax[o] = m2;
  }
}

// ---------------- kernel 2: reduce chunks, compute g_hw gate per n ----------------
__global__ __launch_bounds__(64) void k_ghw(const float* __restrict__ psum,
                                            const float* __restrict__ pmax,
                                            const float* __restrict__ cw,
                                            const float* __restrict__ cb,
                                            const float* __restrict__ bnw,
                                            const float* __restrict__ bnb,
                                            const float* __restrict__ bnrm,
                                            const float* __restrict__ bnrv,
                                            float* __restrict__ ghw) {
  const int n = blockIdx.x;
  const int t = threadIdx.x;
  __shared__ float p2c[2][13][13];
  __shared__ float s_cw[98];

  for (int i = t; i < 2 * 13 * 13; i += 64) ((float*)p2c)[i] = 0.f;
  for (int i = t; i < 98; i += 64) s_cw[i] = cw[i];
  __syncthreads();

  if (t < HW_) {
    float sm = 0.f, mx = -3.4e38f;
    const float* ps = psum + (size_t)n * NCHUNK * HW_ + t;
    const float* pm = pmax + (size_t)n * NCHUNK * HW_ + t;
    #pragma unroll
    for (int cc = 0; cc < NCHUNK; ++cc) {
      sm += ps[cc * HW_];
      mx = fmaxf(mx, pm[cc * HW_]);
    }
    p2c[0][t / 7 + 3][t % 7 + 3] = sm * (1.f / C_);
    p2c[1][t / 7 + 3][t % 7 + 3] = mx;
  }
  __syncthreads();

  if (t < HW_) {
    int a = t / 7, b = t % 7;
    float y = cb[0];
    #pragma unroll
    for (int i2 = 0; i2 < 2; ++i2)
      #pragma unroll
      for (int p = 0; p < 7; ++p)
        #pragma unroll
        for (int q = 0; q < 7; ++q)
          y += p2c[i2][a + p][b + q] * s_cw[i2 * 49 + p * 7 + q];
    float sc = bnw[0] * rsqrtf(bnrv[0] + 1e-5f);
    y = (y - bnrm[0]) * sc + bnb[0];
    y = fmaxf(y, 0.f);
    ghw[n * HW_ + t] = 1.f / (1.f + __expf(-y));
  }
}

// ---------------- kernel 3: W/H pools, g_ch/g_cw gates, fused multiply ----------------
// LDS: sx[3432] + pool_lo[1120] + pool_hi[1120] + gch[448] + gcw[448]
//      + s_w[112] + s_ghw[49] = 6729 floats = 26.9 KB -> 6 blocks/CU.
__global__ __launch_bounds__(256, 6) void k_main(const float* __restrict__ x,
    const float* __restrict__ ghw,
    const float* __restrict__ cw, const float* __restrict__ cb,
    const float* __restrict__ bnw, const float* __restrict__ bnb,
    const float* __restrict__ bnrm, const float* __restrict__ bnrv,
    float* __restrict__ out) {
  const int cc = blockIdx.x;
  const int n  = (N_ - 1) - blockIdx.y;
  const int c0 = cc * CPB;
  const int t  = threadIdx.x;

  __shared__ __align__(16) float sx[3432];       // 70ch x 49 (+gap at 147)
  __shared__ __align__(16) float pool_lo[1120];  // [4][2][35][4]: k=0..3
  __shared__ __align__(16) float pool_hi[1120];  // [4][2][35][4]: k=4..6 (+pad)
  __shared__ float gch[448];                     // [64][7]
  __shared__ float gcw[448];
  __shared__ __align__(16) float s_w[112];       // [2][7][8] weights, q-padded
  __shared__ float s_ghw[49];

  // P2 thread map (t < 128): conv = t&1, i2 = (t>>1)&1, cg = t>>2 in [0,32)
  const int conv = t & 1, i2 = (t >> 1) & 1, cg = t >> 2;
  const int bi = 1 + conv;
  const float cb0 = cb[0];
  const float sc_bn = bnw[bi] * rsqrtf(bnrv[bi] + 1e-5f);
  const float rm_bn = bnrm[bi];
  const float sh_bn = bnb[bi];

  // ---- phase 0: stage ----
  if (t < 112) {
    int i2w = t / 56, rem = t % 56, p = rem / 8, q = rem % 8;
    s_w[t] = (q < 7) ? cw[i2w * 49 + p * 7 + q] : 0.f;
  }
  if (t < HW_) s_ghw[t] = ghw[n * HW_ + t];
  for (int i = t; i < 2 * 3 * HW_; i += 256) {   // halo channels first
    int side = i / 147, off = i % 147;
    int lc = side ? (67 + off / HW_) : (off / HW_);
    int c = c0 - 3 + lc;
    float vv = 0.f;
    if (c >= 0 && c < C_) vv = x[((size_t)n * C_ + c) * HW_ + off % HW_];
    sx[CHB(lc) + off % HW_] = vv;
  }
  const float4* xv = (const float4*)(x + ((size_t)n * C_ + c0) * HW_);
  float4* sxv = (float4*)(sx + 148);
  for (int v = t; v < 784; v += 256) sxv[v] = xv[v];
  __syncthreads();

  // ---- phase 1: W-pools / H-pools for all 70 local channels ----
  for (int i = t; i < 70 * 7; i += 256) {
    int lc = i / 7, k = i % 7;
    int base = CHB(lc);
    float s1 = 0.f, m1 = -3.4e38f, s2 = 0.f, m2 = -3.4e38f;
    #pragma unroll
    for (int j = 0; j < 7; ++j) {
      float a = sx[base + k * 7 + j];   // h=k, vary w  -> W-reduction (g_ch input)
      s1 += a; m1 = fmaxf(m1, a);
      float b = sx[base + j * 7 + k];   // w=k, vary h  -> H-reduction (g_cw input)
      s2 += b; m2 = fmaxf(m2, b);
    }
    float* pb = (k < 4) ? pool_lo : pool_hi;
    int kk = k & 3;
    pb[pool_idx(0, lc, kk)] = s1 * (1.f / 7.f);  // f=0: conv0 mean
    pb[pool_idx(1, lc, kk)] = m1;                // f=1: conv0 max
    pb[pool_idx(2, lc, kk)] = s2 * (1.f / 7.f);  // f=2: conv1 mean
    pb[pool_idx(3, lc, kk)] = m2;                // f=3: conv1 max
  }
  __syncthreads();

  // ---- phase 2: conv, B=2 channels/thread, rolling 2-row window ----
  if (t < 128) {
    const int f = conv * 2 + i2;
    const int r0 = cg * 2;                       // output channels r0, r0+1
    const float* Wb = s_w + i2 * 56;             // [7][8]
    float A[8], B[8];
    float acc0[7] = {0,0,0,0,0,0,0};
    float acc1[7] = {0,0,0,0,0,0,0};

#define LOADROW(D, R) { \
    int oo = pool_idx(f, (R), 0); \
    float4 lo4 = *(const float4*)(pool_lo + oo); \
    float4 hi4 = *(const float4*)(pool_hi + oo); \
    D[0]=lo4.x; D[1]=lo4.y; D[2]=lo4.z; D[3]=lo4.w; \
    D[4]=hi4.x; D[5]=hi4.y; D[6]=hi4.z; D[7]=hi4.w; }

#define STEP(P, RL, RH) { \
    float4 w0 = *(const float4*)(Wb + (P) * 8); \
    float4 w1 = *(const float4*)(Wb + (P) * 8 + 4); \
    float wr[7] = {w0.x, w0.y, w0.z, w0.w, w1.x, w1.y, w1.z}; \
    _Pragma("unroll") \
    for (int q = 0; q < 7; ++q) { \
      _Pragma("unroll") \
      for (int k = 0; k < 7; ++k) { \
        int c = k + q - 3; \
        if (c >= 0 && c < 7) { acc0[k] += RL[c] * wr[q]; acc1[k] += RH[c] * wr[q]; } \
      } } }

    LOADROW(A, r0);
    LOADROW(B, r0 + 1);
    STEP(0, A, B);
    LOADROW(A, r0 + 2); STEP(1, B, A);
    LOADROW(B, r0 + 3); STEP(2, A, B);
    LOADROW(A, r0 + 4); STEP(3, B, A);
    LOADROW(B, r0 + 5); STEP(4, A, B);
    LOADROW(A, r0 + 6); STEP(5, B, A);
    LOADROW(B, r0 + 7); STEP(6, A, B);
#undef LOADROW
#undef STEP

    // combine i2 halves: partner lane = t ^ 2
    float f0[7], f1[7];
    #pragma unroll
    for (int k = 0; k < 7; ++k) {
      f0[k] = acc0[k] + __shfl_xor(acc0[k], 2, 64);
      f1[k] = acc1[k] + __shfl_xor(acc1[k], 2, 64);
    }
    if (i2 == 0) {
      float* gp = (conv ? gcw : gch);
      #pragma unroll
      for (int k = 0; k < 7; ++k) {
        float y0 = (f0[k] + cb0 - rm_bn) * sc_bn + sh_bn;
        float y1 = (f1[k] + cb0 - rm_bn) * sc_bn + sh_bn;
        y0 = fmaxf(y0, 0.f);
        y1 = fmaxf(y1, 0.f);
        gp[r0 * 7 + k]       = 1.f / (1.f + __expf(-y0));
        gp[(r0 + 1) * 7 + k] = 1.f / (1.f + __expf(-y1));
      }
    }
  }
  __syncthreads();

  // ---- phase 3: fused multiply, LDS re-read (b128), float4 stores ----
  float4* outv = (float4*)(out + ((size_t)n * C_ + c0) * HW_);
  for (int v = t; v < 784; v += 256) {
    float4 q = sxv[v];
    int e0 = v * 4;
    int cj = e0 / 49;
    int hw0 = e0 - cj * 49;
    float r0 = q.x, r1 = q.y, r2 = q.z, r3 = q.w;
    {
      int hw = hw0;
      int cjj = cj + (hw >= 49); hw -= (hw >= 49) ? 49 : 0;
      int h = (hw * 37) >> 8, w2 = hw - h * 7;
      r0 *= (s_ghw[hw] + gch[cjj * 7 + h] + gcw[cjj * 7 + w2]) * (1.f / 3.f);
    }
    {
      int hw = hw0 + 1;
      int cjj = cj + (hw >= 49); hw -= (hw >= 49) ? 49 : 0;
      int h = (hw * 37) >> 8, w2 = hw - h * 7;
      r1 *= (s_ghw[hw] + gch[cjj * 7 + h] + gcw[cjj * 7 + w2]) * (1.f / 3.f);
    }
    {
      int hw = hw0 + 2;
      int cjj = cj + (hw >= 49); hw -= (hw >= 49) ? 49 : 0;
      int h = (hw * 37) >> 8, w2 = hw - h * 7;
      r2 *= (s_ghw[hw] + gch[cjj * 7 + h] + gcw[cjj * 7 + w2]) * (1.f / 3.f);
    }
    {
      int hw = hw0 + 3;
      int cjj = cj + (hw >= 49); hw -= (hw >= 49) ? 49 : 0;
      int h = (hw * 37) >> 8, w2 = hw - h * 7;
      r3 *= (s_ghw[hw] + gch[cjj * 7 + h] + gcw[cjj * 7 + w2]) * (1.f / 3.f);
    }
    outv[v] = make_float4(r0, r1, r2, r3);
  }
}

extern "C" void kernel_launch(void* const* d_in, const int* in_sizes, int n_in,
                              void* d_out, int out_size, void* d_ws, size_t ws_size,
                              hipStream_t stream) {
  const float* x    = (const float*)d_in[0];
  const float* cw   = (const float*)d_in[1];
  const float* cb   = (const float*)d_in[2];
  const float* bnw  = (const float*)d_in[3];
  const float* bnb  = (const float*)d_in[4];
  const float* bnrm = (const float*)d_in[5];
  const float* bnrv = (const float*)d_in[6];
  float* out = (float*)d_out;

  float* psum = (float*)d_ws;                         // N*8*49
  float* pmax = psum + (size_t)N_ * NCHUNK * HW_;     // N*8*49
  float* ghw  = pmax + (size_t)N_ * NCHUNK * HW_;     // N*49

  k_poolc<<<dim3(NCHUNK, N_), 256, 0, stream>>>(x, psum, pmax);
  k_ghw<<<dim3(N_), 64, 0, stream>>>(psum, pmax, cw, cb, bnw, bnb, bnrm, bnrv, ghw);
  k_main<<<dim3(NCC, N_), 256, 0, stream>>>(x, ghw, cw, cb, bnw, bnb, bnrm, bnrv, out);
}